// Round 1
// baseline (787.875 us; speedup 1.0000x reference)
//
#include <hip/hip_runtime.h>

#define NDET 50000
#define DEG 32
#define NEDGE (NDET * DEG)

// ---------------------------------------------------------------------------
// Kernel A: h = relu(detF @ W_fc1 + b_fc1)   [NDET,128] -> [NDET,32]
// block 256 = 8 rows x 32 cols
// ---------------------------------------------------------------------------
__global__ __launch_bounds__(256) void fc1_kernel(
    const float* __restrict__ detF,
    const float* __restrict__ W,    // [128][32] row-major (in,out)
    const float* __restrict__ b,    // [32]
    float* __restrict__ h)          // [NDET][32]
{
    __shared__ float Ws[128 * 32];
    for (int i = threadIdx.x; i < 128 * 32; i += 256) Ws[i] = W[i];
    __syncthreads();

    const int row = blockIdx.x * 8 + (threadIdx.x >> 5);
    const int c   = threadIdx.x & 31;
    if (row >= NDET) return;

    const float4* df4 = (const float4*)(detF + (size_t)row * 128);
    float acc = b[c];
#pragma unroll
    for (int i = 0; i < 32; i++) {
        float4 d = df4[i];
        acc += d.x * Ws[(4 * i + 0) * 32 + c];
        acc += d.y * Ws[(4 * i + 1) * 32 + c];
        acc += d.z * Ws[(4 * i + 2) * 32 + c];
        acc += d.w * Ws[(4 * i + 3) * 32 + c];
    }
    h[(size_t)row * 32 + c] = fmaxf(acc, 0.0f);
}

// ---------------------------------------------------------------------------
// Kernel B: fused edge MLP (pw1 -> relu -> pw2 -> relu) + segment max.
// One block-iteration = 2 detections = 64 edges. Tile 64 edges x 64 outputs,
// 256 threads, each thread 4 edges x 4 outputs.
// Center-feature contribution (identical across a det's 32 edges) is hoisted
// into the accumulator init, so the MLP1 K-loop is 64 (pair 32 + nbr 32).
// ---------------------------------------------------------------------------
#define XT(k, e) XtBuf[(k) * 68 + (e)]

__global__ __launch_bounds__(256) void edge_kernel(
    const float* __restrict__ h,      // [NDET][32]
    const int* __restrict__ cIdx,     // [NEDGE]
    const int* __restrict__ nIdx,     // [NEDGE]
    const float* __restrict__ pairF,  // [NEDGE][32]
    const float* __restrict__ W1,     // [96][64]
    const float* __restrict__ b1,     // [64]
    const float* __restrict__ W2,     // [64][64]
    const float* __restrict__ b2,     // [64]
    float* __restrict__ m)            // [NDET][64]
{
    __shared__ float W1s[64 * 64];   // k 0..31: W1 rows 0..31 (pair); k 32..63: W1 rows 64..95 (nbr)
    __shared__ float W1c[32 * 64];   // W1 rows 32..63 (center)
    __shared__ float W2s[64 * 64];
    __shared__ float b1s[64], b2s[64];
    __shared__ float XtBuf[64 * 68]; // transposed input tile; reused as Y1^T
    __shared__ float cc[2][64];      // per-det hoisted center contribution (incl. b1)
    __shared__ float Red[16][68];    // partial maxes

    const int tid = threadIdx.x;

    for (int i = tid; i < 64 * 64; i += 256) {
        int k = i >> 6, o = i & 63;
        W1s[i] = W1[(k < 32 ? k : k + 32) * 64 + o];
        W2s[i] = W2[i];
    }
    for (int i = tid; i < 32 * 64; i += 256)
        W1c[i] = W1[(32 + (i >> 6)) * 64 + (i & 63)];
    if (tid < 64) { b1s[tid] = b1[tid]; b2s[tid] = b2[tid]; }

    const int tx = tid & 15;    // output group: o0..o0+3
    const int ey = tid >> 4;    // edge group:  4*ey..4*ey+3
    const int o0 = tx * 4;
    const int e0 = ey * 4;
    const int dl = ey >> 3;     // det-local index of this thread's edges (0/1)

    const int NGROUP = NDET / 2;  // 25000
    for (int g = blockIdx.x; g < NGROUP; g += (int)gridDim.x) {
        const int d0 = g * 2;
        const int E0 = g * 64;
        __syncthreads();  // protect LDS reuse across iterations (and weights on iter 0)

        // ---- stage pair rows (transposed): Xt[0..31][le] ----
        {
            const float4* pf4 = (const float4*)pairF + (size_t)E0 * 8;
#pragma unroll
            for (int rep = 0; rep < 2; rep++) {
                int f = tid + rep * 256;         // 0..511
                int le = f >> 3, j = f & 7;
                float4 v = pf4[f];
                XT(4 * j + 0, le) = v.x;
                XT(4 * j + 1, le) = v.y;
                XT(4 * j + 2, le) = v.z;
                XT(4 * j + 3, le) = v.w;
            }
        }
        // ---- stage neighbor rows (transposed, zero on identity): Xt[32..63][le] ----
        {
            int le = tid >> 2, p = tid & 3;      // 4 threads per edge
            int e = E0 + le;
            int c = cIdx[e], n = nIdx[e];
            float4 a, bb;
            if (c == n) {
                a = make_float4(0.f, 0.f, 0.f, 0.f);
                bb = a;
            } else {
                const float4* h4 = (const float4*)h + (size_t)n * 8;
                a  = h4[2 * p];
                bb = h4[2 * p + 1];
            }
            int kb = 32 + 8 * p;
            XT(kb + 0, le) = a.x;  XT(kb + 1, le) = a.y;
            XT(kb + 2, le) = a.z;  XT(kb + 3, le) = a.w;
            XT(kb + 4, le) = bb.x; XT(kb + 5, le) = bb.y;
            XT(kb + 6, le) = bb.z; XT(kb + 7, le) = bb.w;
        }
        // ---- hoisted center contribution: cc[d][o] = b1[o] + h[d0+d].W1c[:,o] ----
        if (tid < 128) {
            int d = tid >> 6, o = tid & 63;
            const float* hr = h + (size_t)(d0 + d) * 32;
            float acc = b1s[o];
#pragma unroll
            for (int k = 0; k < 32; k++) acc += hr[k] * W1c[k * 64 + o];
            cc[d][o] = acc;
        }
        __syncthreads();

        // ---- MLP1 GEMM: K=64 ----
        float acc[4][4];
#pragma unroll
        for (int i = 0; i < 4; i++)
#pragma unroll
            for (int j = 0; j < 4; j++) acc[i][j] = cc[dl][o0 + j];

#pragma unroll 8
        for (int k = 0; k < 64; k++) {
            const float4 x = *(const float4*)&XT(k, e0);
            const float4 w = *(const float4*)&W1s[(k << 6) + o0];
            acc[0][0] += x.x * w.x; acc[0][1] += x.x * w.y; acc[0][2] += x.x * w.z; acc[0][3] += x.x * w.w;
            acc[1][0] += x.y * w.x; acc[1][1] += x.y * w.y; acc[1][2] += x.y * w.z; acc[1][3] += x.y * w.w;
            acc[2][0] += x.z * w.x; acc[2][1] += x.z * w.y; acc[2][2] += x.z * w.z; acc[2][3] += x.z * w.w;
            acc[3][0] += x.w * w.x; acc[3][1] += x.w * w.y; acc[3][2] += x.w * w.z; acc[3][3] += x.w * w.w;
        }
        __syncthreads();
        // write Y1^T = relu(acc) into the Xt buffer
#pragma unroll
        for (int j = 0; j < 4; j++)
#pragma unroll
            for (int i = 0; i < 4; i++)
                XT(o0 + j, e0 + i) = fmaxf(acc[i][j], 0.0f);
        __syncthreads();

        // ---- MLP2 GEMM: K=64 ----
        float acc2[4][4];
#pragma unroll
        for (int i = 0; i < 4; i++)
#pragma unroll
            for (int j = 0; j < 4; j++) acc2[i][j] = b2s[o0 + j];

#pragma unroll 8
        for (int k = 0; k < 64; k++) {
            const float4 x = *(const float4*)&XT(k, e0);
            const float4 w = *(const float4*)&W2s[(k << 6) + o0];
            acc2[0][0] += x.x * w.x; acc2[0][1] += x.x * w.y; acc2[0][2] += x.x * w.z; acc2[0][3] += x.x * w.w;
            acc2[1][0] += x.y * w.x; acc2[1][1] += x.y * w.y; acc2[1][2] += x.y * w.z; acc2[1][3] += x.y * w.w;
            acc2[2][0] += x.z * w.x; acc2[2][1] += x.z * w.y; acc2[2][2] += x.z * w.z; acc2[2][3] += x.z * w.w;
            acc2[3][0] += x.w * w.x; acc2[3][1] += x.w * w.y; acc2[3][2] += x.w * w.z; acc2[3][3] += x.w * w.w;
        }

        // per-thread max over its 4 edges (relu folded in; y2 >= 0 after relu)
#pragma unroll
        for (int j = 0; j < 4; j++) {
            float v = acc2[0][j];
            v = fmaxf(v, acc2[1][j]);
            v = fmaxf(v, acc2[2][j]);
            v = fmaxf(v, acc2[3][j]);
            Red[ey][o0 + j] = fmaxf(v, 0.0f);
        }
        __syncthreads();
        // reduce 8 edge-groups per det, store m
        if (tid < 128) {
            int dd = tid >> 6, o = tid & 63;
            float v = Red[8 * dd + 0][o];
#pragma unroll
            for (int r = 1; r < 8; r++) v = fmaxf(v, Red[8 * dd + r][o]);
            m[(size_t)(d0 + dd) * 64 + o] = v;
        }
    }
}

// ---------------------------------------------------------------------------
// Kernel C: tail — relu(m@Wpm1+b) -> relu(@Wpm2+b) -> @Wout+b -> relu(detF + .)
// 64 threads per detection, 4 detections per block-iteration.
// ---------------------------------------------------------------------------
__global__ __launch_bounds__(256) void tail_kernel(
    const float* __restrict__ detF,   // [NDET][128]
    const float* __restrict__ m,      // [NDET][64]
    const float* __restrict__ Wm1, const float* __restrict__ bm1,
    const float* __restrict__ Wm2, const float* __restrict__ bm2,
    const float* __restrict__ Wo,  const float* __restrict__ bo,
    float* __restrict__ out)          // [NDET][128]
{
    __shared__ float Wm1s[64 * 64], Wm2s[64 * 64];
    __shared__ float Wos[64 * 128];
    __shared__ float bm1s[64], bm2s[64], bos[128];
    __shared__ float ms[4][65], t1[4][65], t2[4][65];

    const int tid = threadIdx.x;
    for (int i = tid; i < 64 * 64; i += 256) { Wm1s[i] = Wm1[i]; Wm2s[i] = Wm2[i]; }
    for (int i = tid; i < 64 * 128; i += 256) Wos[i] = Wo[i];
    if (tid < 64) { bm1s[tid] = bm1[tid]; bm2s[tid] = bm2[tid]; }
    if (tid < 128) bos[tid] = bo[tid];

    const int d = tid >> 6;   // 0..3
    const int o = tid & 63;

    const int NG = NDET / 4;  // 12500
    for (int g = blockIdx.x; g < NG; g += (int)gridDim.x) {
        const int d0 = g * 4;
        __syncthreads();
        ms[d][o] = m[(size_t)(d0 + d) * 64 + o];
        __syncthreads();

        float acc = bm1s[o];
#pragma unroll 8
        for (int k = 0; k < 64; k++) acc += ms[d][k] * Wm1s[k * 64 + o];
        t1[d][o] = fmaxf(acc, 0.0f);
        __syncthreads();

        acc = bm2s[o];
#pragma unroll 8
        for (int k = 0; k < 64; k++) acc += t1[d][k] * Wm2s[k * 64 + o];
        t2[d][o] = fmaxf(acc, 0.0f);
        __syncthreads();

        float a0 = bos[o], a1 = bos[o + 64];
#pragma unroll 8
        for (int k = 0; k < 64; k++) {
            float v = t2[d][k];
            a0 += v * Wos[k * 128 + o];
            a1 += v * Wos[k * 128 + o + 64];
        }
        const float* dfr = detF + (size_t)(d0 + d) * 128;
        out[(size_t)(d0 + d) * 128 + o]      = fmaxf(dfr[o] + a0, 0.0f);
        out[(size_t)(d0 + d) * 128 + 64 + o] = fmaxf(dfr[o + 64] + a1, 0.0f);
    }
}

// ---------------------------------------------------------------------------
extern "C" void kernel_launch(void* const* d_in, const int* in_sizes, int n_in,
                              void* d_out, int out_size, void* d_ws, size_t ws_size,
                              hipStream_t stream)
{
    const float* detF  = (const float*)d_in[0];
    const int*   cIdx  = (const int*)d_in[1];
    const int*   nIdx  = (const int*)d_in[2];
    const float* pairF = (const float*)d_in[3];
    const float* W_fc1 = (const float*)d_in[4];
    const float* b_fc1 = (const float*)d_in[5];
    const float* W_pw1 = (const float*)d_in[6];
    const float* b_pw1 = (const float*)d_in[7];
    const float* W_pw2 = (const float*)d_in[8];
    const float* b_pw2 = (const float*)d_in[9];
    const float* W_pm1 = (const float*)d_in[10];
    const float* b_pm1 = (const float*)d_in[11];
    const float* W_pm2 = (const float*)d_in[12];
    const float* b_pm2 = (const float*)d_in[13];
    const float* W_out = (const float*)d_in[14];
    const float* b_out = (const float*)d_in[15];
    float* out = (float*)d_out;

    float* h = (float*)d_ws;                  // [NDET][32]  = 6.4 MB
    float* m = h + (size_t)NDET * 32;         // [NDET][64]  = 12.8 MB

    fc1_kernel<<<NDET / 8, 256, 0, stream>>>(detF, W_fc1, b_fc1, h);
    edge_kernel<<<2048, 256, 0, stream>>>(h, cIdx, nIdx, pairF,
                                          W_pw1, b_pw1, W_pw2, b_pw2, m);
    tail_kernel<<<1280, 256, 0, stream>>>(detF, m, W_pm1, b_pm1, W_pm2, b_pm2,
                                          W_out, b_out, out);
}

// Round 2
// 581.480 us; speedup vs baseline: 1.3549x; 1.3549x over previous
//
#include <hip/hip_runtime.h>

#define NDET 50000
#define DEG 32
#define NEDGE (NDET * DEG)

typedef __attribute__((ext_vector_type(8))) short short8;
typedef __attribute__((ext_vector_type(4))) float f32x4;

__device__ inline unsigned short f2bf(float x) {
    unsigned int u = __builtin_bit_cast(unsigned int, x);
    unsigned int r = (u + 0x7FFFu + ((u >> 16) & 1u)) >> 16;
    return (unsigned short)r;
}
__device__ inline float bf2f(unsigned short b) {
    unsigned int u = ((unsigned int)b) << 16;
    return __builtin_bit_cast(float, u);
}

// ---------------------------------------------------------------------------
// Kernel A: h = relu(detF @ W_fc1 + b_fc1)   [NDET,128] -> [NDET,32]  (fp32)
// grid-stride: stage weights once per block.
// ---------------------------------------------------------------------------
__global__ __launch_bounds__(256) void fc1_kernel(
    const float* __restrict__ detF,
    const float* __restrict__ W,    // [128][32]
    const float* __restrict__ b,
    float* __restrict__ h)          // [NDET][32]
{
    __shared__ float Ws[128 * 32];
    for (int i = threadIdx.x; i < 128 * 32; i += 256) Ws[i] = W[i];
    __syncthreads();

    const int c = threadIdx.x & 31;
    const float bc = b[c];
    const int NG = NDET / 8;  // 6250
    for (int rg = blockIdx.x; rg < NG; rg += (int)gridDim.x) {
        const int row = rg * 8 + (threadIdx.x >> 5);
        const float4* df4 = (const float4*)(detF + (size_t)row * 128);
        float acc = bc;
#pragma unroll
        for (int i = 0; i < 32; i++) {
            float4 d = df4[i];
            acc += d.x * Ws[(4 * i + 0) * 32 + c];
            acc += d.y * Ws[(4 * i + 1) * 32 + c];
            acc += d.z * Ws[(4 * i + 2) * 32 + c];
            acc += d.w * Ws[(4 * i + 3) * 32 + c];
        }
        h[(size_t)row * 32 + c] = fmaxf(acc, 0.0f);
    }
}

// ---------------------------------------------------------------------------
// Kernel B: fused edge MLP via bf16 MFMA + segment max.
// Block = 4 waves; each WAVE independently processes one group of 2 dets
// (64 edges) per iteration. No __syncthreads inside the loop (wave-private
// LDS tiles; DS ops within a wave are ordered).
//
// MFMA 16x16x32 bf16 layout (m89/m120-verified):
//   A-frag: lane holds A[m = lane&15][k = (lane>>4)*8 + j], j=0..7
//   B-frag: lane holds B[k = (lane>>4)*8 + j][n = lane&15]
//   D:      lane reg r holds D[row = (lane>>4)*4 + r][col = lane&15]
//
// MLP1: X[64 edges][K=64] (pair 0..31 | neighbor 32..63) @ W1' -> Y1
//       center contribution hoisted into acc init (cc), K reduced 96->64.
// MLP2: Y1[64][64] @ W2 -> Z; relu; per-det max over 32 edges via
//       per-lane max + shfl_xor(16/32) across quads.
// ---------------------------------------------------------------------------
__global__ __launch_bounds__(256, 2) void edge_kernel(
    const float* __restrict__ h,      // [NDET][32] fp32
    const int* __restrict__ nIdx,     // [NEDGE]
    const float* __restrict__ pairF,  // [NEDGE][32] fp32
    const float* __restrict__ W1,     // [96][64]
    const float* __restrict__ b1,     // [64]
    const float* __restrict__ W2,     // [64][64]
    const float* __restrict__ b2,     // [64]
    float* __restrict__ m_out)        // [NDET][64] fp32
{
    // per-wave tiles, rows padded to 72 bf16 (144 B; 16B-aligned, 2-way banks)
    __shared__ __align__(16) unsigned short Xs[4][64 * 72];   // 36864 B
    __shared__ __align__(16) unsigned short Y1s[4][64 * 72];  // 36864 B (waves 0/1 double as weight staging)
    __shared__ unsigned short W1c[32 * 64];                   // 4096 B  (center weights, bf16)
    __shared__ float ccs[4][2][64];                           // 2048 B
    // total 79872 B -> 2 blocks/CU

    const int tid  = threadIdx.x;
    const int lane = tid & 63;
    const int wv   = tid >> 6;
    const int m16  = lane & 15;
    const int q    = lane >> 4;

    // ---- stage weights (bf16, transposed for B-frags) into Y1s[0]/Y1s[1] ----
    for (int i = tid; i < 64 * 64; i += 256) {
        int k = i >> 6, n = i & 63;
        float v = (k < 32) ? W1[k * 64 + n] : W1[(k + 32) * 64 + n];  // pair rows | neighbor rows
        Y1s[0][n * 72 + k] = f2bf(v);
        Y1s[1][n * 72 + k] = f2bf(W2[i]);
    }
    for (int i = tid; i < 32 * 64; i += 256)
        W1c[i] = f2bf(W1[(32 + (i >> 6)) * 64 + (i & 63)]);
    __syncthreads();

    // ---- load weight fragments into registers (held for the whole kernel) ----
    short8 w1f[2][4], w2f[2][4];
#pragma unroll
    for (int ks = 0; ks < 2; ks++)
#pragma unroll
        for (int nt = 0; nt < 4; nt++) {
            w1f[ks][nt] = *(const short8*)&Y1s[0][(nt * 16 + m16) * 72 + ks * 32 + q * 8];
            w2f[ks][nt] = *(const short8*)&Y1s[1][(nt * 16 + m16) * 72 + ks * 32 + q * 8];
        }
    const float b1v = b1[lane];
    float b2r[4];
#pragma unroll
    for (int nt = 0; nt < 4; nt++) b2r[nt] = b2[nt * 16 + m16];
    __syncthreads();  // Y1s staging area free for reuse

    unsigned short* Xw  = &Xs[wv][0];
    unsigned short* Y1w = &Y1s[wv][0];

    const int NGROUP = NEDGE / 64;  // 25000 (2 dets each)
    const int wslots = (int)gridDim.x * 4;
    for (int g = blockIdx.x * 4 + wv; g < NGROUP; g += wslots) {
        const int d0 = g * 2;
        const int E0 = g * 64;

        // ---- stage pair features: X[e][0..31] ----
        {
            const float4* pf4 = (const float4*)pairF + (size_t)E0 * 8;
#pragma unroll
            for (int it = 0; it < 8; it++) {
                int f = it * 64 + lane;            // coalesced
                int e = f >> 3, j = f & 7;
                float4 v = pf4[f];
                ushort4 u = make_ushort4(f2bf(v.x), f2bf(v.y), f2bf(v.z), f2bf(v.w));
                *(ushort4*)&Xw[e * 72 + j * 4] = u;
            }
        }
        // ---- stage neighbor features: X[e][32..63], zero on identity ----
        {
#pragma unroll
            for (int it = 0; it < 8; it++) {
                int f = it * 64 + lane;
                int e = f >> 3, j = f & 7;
                int eg = E0 + e;
                int n = nIdx[eg];
                int c = eg >> 5;                   // cIdx[e] == e/32 by construction
                float4 v;
                if (n == c) v = make_float4(0.f, 0.f, 0.f, 0.f);
                else        v = ((const float4*)h)[(size_t)n * 8 + j];
                ushort4 u = make_ushort4(f2bf(v.x), f2bf(v.y), f2bf(v.z), f2bf(v.w));
                *(ushort4*)&Xw[e * 72 + 32 + j * 4] = u;
            }
        }
        // ---- hoisted center contribution: cc[d][o] = b1[o] + h[d0+d,:] . W1c[:,o] ----
        {
            const float* h0 = h + (size_t)d0 * 32;
            float a0 = b1v, a1 = b1v;
#pragma unroll 8
            for (int k = 0; k < 32; k++) {
                float w = bf2f(W1c[k * 64 + lane]);
                a0 += h0[k] * w;        // uniform (scalar) loads
                a1 += h0[32 + k] * w;
            }
            ccs[wv][0][lane] = a0;
            ccs[wv][1][lane] = a1;
        }
        float ccv[2][4];
#pragma unroll
        for (int d = 0; d < 2; d++)
#pragma unroll
            for (int nt = 0; nt < 4; nt++) ccv[d][nt] = ccs[wv][d][nt * 16 + m16];

        // ---- MLP1: acc[mt][nt] = X-tile(mt) @ W1-tile(nt), init = cc ----
        f32x4 acc[4][4];
#pragma unroll
        for (int mt = 0; mt < 4; mt++)
#pragma unroll
            for (int nt = 0; nt < 4; nt++) {
                float c0 = ccv[mt >> 1][nt];       // det = mt>>1 (rows mt*16+q*4+r)
                acc[mt][nt] = (f32x4){c0, c0, c0, c0};
            }
#pragma unroll
        for (int ks = 0; ks < 2; ks++) {
            short8 af[4];
#pragma unroll
            for (int mt = 0; mt < 4; mt++)
                af[mt] = *(const short8*)&Xw[(mt * 16 + m16) * 72 + ks * 32 + q * 8];
#pragma unroll
            for (int mt = 0; mt < 4; mt++)
#pragma unroll
                for (int nt = 0; nt < 4; nt++)
                    acc[mt][nt] = __builtin_amdgcn_mfma_f32_16x16x32_bf16(
                        af[mt], w1f[ks][nt], acc[mt][nt], 0, 0, 0);
        }
        // ---- relu -> Y1 (bf16, D-layout -> row-major) ----
#pragma unroll
        for (int mt = 0; mt < 4; mt++)
#pragma unroll
            for (int nt = 0; nt < 4; nt++)
#pragma unroll
                for (int r = 0; r < 4; r++) {
                    float v = fmaxf(acc[mt][nt][r], 0.0f);
                    Y1w[(mt * 16 + q * 4 + r) * 72 + nt * 16 + m16] = f2bf(v);
                }

        // ---- MLP2 ----
        f32x4 acc2[4][4];
#pragma unroll
        for (int mt = 0; mt < 4; mt++)
#pragma unroll
            for (int nt = 0; nt < 4; nt++) {
                float c0 = b2r[nt];
                acc2[mt][nt] = (f32x4){c0, c0, c0, c0};
            }
#pragma unroll
        for (int ks = 0; ks < 2; ks++) {
            short8 af[4];
#pragma unroll
            for (int mt = 0; mt < 4; mt++)
                af[mt] = *(const short8*)&Y1w[(mt * 16 + m16) * 72 + ks * 32 + q * 8];
#pragma unroll
            for (int mt = 0; mt < 4; mt++)
#pragma unroll
                for (int nt = 0; nt < 4; nt++)
                    acc2[mt][nt] = __builtin_amdgcn_mfma_f32_16x16x32_bf16(
                        af[mt], w2f[ks][nt], acc2[mt][nt], 0, 0, 0);
        }

        // ---- relu + segment max (32 edges/det) + store m ----
#pragma unroll
        for (int d = 0; d < 2; d++)
#pragma unroll
            for (int nt = 0; nt < 4; nt++) {
                float v = 0.0f;  // relu floor
#pragma unroll
                for (int mt = 2 * d; mt < 2 * d + 2; mt++)
#pragma unroll
                    for (int r = 0; r < 4; r++) v = fmaxf(v, acc2[mt][nt][r]);
                v = fmaxf(v, __shfl_xor(v, 16));
                v = fmaxf(v, __shfl_xor(v, 32));
                if (q == 0) m_out[(size_t)(d0 + d) * 64 + nt * 16 + m16] = v;
            }
    }
}

// ---------------------------------------------------------------------------
// Kernel C: tail (unchanged, fp32)
// ---------------------------------------------------------------------------
__global__ __launch_bounds__(256) void tail_kernel(
    const float* __restrict__ detF,
    const float* __restrict__ m,
    const float* __restrict__ Wm1, const float* __restrict__ bm1,
    const float* __restrict__ Wm2, const float* __restrict__ bm2,
    const float* __restrict__ Wo,  const float* __restrict__ bo,
    float* __restrict__ out)
{
    __shared__ float Wm1s[64 * 64], Wm2s[64 * 64];
    __shared__ float Wos[64 * 128];
    __shared__ float bm1s[64], bm2s[64], bos[128];
    __shared__ float ms[4][65], t1[4][65], t2[4][65];

    const int tid = threadIdx.x;
    for (int i = tid; i < 64 * 64; i += 256) { Wm1s[i] = Wm1[i]; Wm2s[i] = Wm2[i]; }
    for (int i = tid; i < 64 * 128; i += 256) Wos[i] = Wo[i];
    if (tid < 64) { bm1s[tid] = bm1[tid]; bm2s[tid] = bm2[tid]; }
    if (tid < 128) bos[tid] = bo[tid];

    const int d = tid >> 6;
    const int o = tid & 63;

    const int NG = NDET / 4;
    for (int g = blockIdx.x; g < NG; g += (int)gridDim.x) {
        const int d0 = g * 4;
        __syncthreads();
        ms[d][o] = m[(size_t)(d0 + d) * 64 + o];
        __syncthreads();

        float acc = bm1s[o];
#pragma unroll 8
        for (int k = 0; k < 64; k++) acc += ms[d][k] * Wm1s[k * 64 + o];
        t1[d][o] = fmaxf(acc, 0.0f);
        __syncthreads();

        acc = bm2s[o];
#pragma unroll 8
        for (int k = 0; k < 64; k++) acc += t1[d][k] * Wm2s[k * 64 + o];
        t2[d][o] = fmaxf(acc, 0.0f);
        __syncthreads();

        float a0 = bos[o], a1 = bos[o + 64];
#pragma unroll 8
        for (int k = 0; k < 64; k++) {
            float v = t2[d][k];
            a0 += v * Wos[k * 128 + o];
            a1 += v * Wos[k * 128 + o + 64];
        }
        const float* dfr = detF + (size_t)(d0 + d) * 128;
        out[(size_t)(d0 + d) * 128 + o]      = fmaxf(dfr[o] + a0, 0.0f);
        out[(size_t)(d0 + d) * 128 + 64 + o] = fmaxf(dfr[o + 64] + a1, 0.0f);
    }
}

// ---------------------------------------------------------------------------
extern "C" void kernel_launch(void* const* d_in, const int* in_sizes, int n_in,
                              void* d_out, int out_size, void* d_ws, size_t ws_size,
                              hipStream_t stream)
{
    const float* detF  = (const float*)d_in[0];
    const int*   cIdx  = (const int*)d_in[1];  (void)cIdx;
    const int*   nIdx  = (const int*)d_in[2];
    const float* pairF = (const float*)d_in[3];
    const float* W_fc1 = (const float*)d_in[4];
    const float* b_fc1 = (const float*)d_in[5];
    const float* W_pw1 = (const float*)d_in[6];
    const float* b_pw1 = (const float*)d_in[7];
    const float* W_pw2 = (const float*)d_in[8];
    const float* b_pw2 = (const float*)d_in[9];
    const float* W_pm1 = (const float*)d_in[10];
    const float* b_pm1 = (const float*)d_in[11];
    const float* W_pm2 = (const float*)d_in[12];
    const float* b_pm2 = (const float*)d_in[13];
    const float* W_out = (const float*)d_in[14];
    const float* b_out = (const float*)d_in[15];
    float* out = (float*)d_out;

    float* h = (float*)d_ws;                  // [NDET][32]
    float* m = h + (size_t)NDET * 32;         // [NDET][64]

    fc1_kernel<<<1024, 256, 0, stream>>>(detF, W_fc1, b_fc1, h);
    edge_kernel<<<512, 256, 0, stream>>>(h, nIdx, pairF,
                                         W_pw1, b_pw1, W_pw2, b_pw2, m);
    tail_kernel<<<1280, 256, 0, stream>>>(detF, m, W_pm1, b_pm1, W_pm2, b_pm2,
                                          W_out, b_out, out);
}

// Round 3
// 463.873 us; speedup vs baseline: 1.6985x; 1.2535x over previous
//
#include <hip/hip_runtime.h>

#define NDET 50000
#define DEG 32
#define NEDGE (NDET * DEG)
#define NGROUP (NEDGE / 64)   // 25000 groups of 2 dets / 64 edges

typedef __attribute__((ext_vector_type(8))) short short8;
typedef __attribute__((ext_vector_type(4))) float f32x4;

__device__ inline unsigned short f2bf(float x) {
    unsigned int u = __builtin_bit_cast(unsigned int, x);
    unsigned int r = (u + 0x7FFFu + ((u >> 16) & 1u)) >> 16;
    return (unsigned short)r;
}

__device__ inline short8 pack8(float4 a, float4 b) {
    short8 r;
    r[0] = (short)f2bf(a.x); r[1] = (short)f2bf(a.y);
    r[2] = (short)f2bf(a.z); r[3] = (short)f2bf(a.w);
    r[4] = (short)f2bf(b.x); r[5] = (short)f2bf(b.y);
    r[6] = (short)f2bf(b.z); r[7] = (short)f2bf(b.w);
    return r;
}

// ---------------------------------------------------------------------------
// Kernel A: hbf = bf16(relu(detF @ W_fc1 + b_fc1))   [NDET,32] bf16
// ---------------------------------------------------------------------------
__global__ __launch_bounds__(256) void fc1_kernel(
    const float* __restrict__ detF,
    const float* __restrict__ W,    // [128][32]
    const float* __restrict__ b,
    unsigned short* __restrict__ hbf)   // [NDET][32] bf16
{
    __shared__ float Ws[128 * 32];
    for (int i = threadIdx.x; i < 128 * 32; i += 256) Ws[i] = W[i];
    __syncthreads();

    const int c = threadIdx.x & 31;
    const float bc = b[c];
    const int NG = NDET / 8;
    for (int rg = blockIdx.x; rg < NG; rg += (int)gridDim.x) {
        const int row = rg * 8 + (threadIdx.x >> 5);
        const float4* df4 = (const float4*)(detF + (size_t)row * 128);
        float acc = bc;
#pragma unroll
        for (int i = 0; i < 32; i++) {
            float4 d = df4[i];
            acc += d.x * Ws[(4 * i + 0) * 32 + c];
            acc += d.y * Ws[(4 * i + 1) * 32 + c];
            acc += d.z * Ws[(4 * i + 2) * 32 + c];
            acc += d.w * Ws[(4 * i + 3) * 32 + c];
        }
        hbf[(size_t)row * 32 + c] = f2bf(fmaxf(acc, 0.0f));
    }
}

// ---------------------------------------------------------------------------
// Kernel B: edge MLP, direct-to-register A-frags + 1-deep prefetch.
// Wave-private; per iteration: 2 dets / 64 edges. MLP1 K=96 (pair|nbr|center),
// MLP2 K=64. Only Y1 round-trips LDS. m output stored bf16.
// A-frag: lane holds A[m=lane&15][k=(lane>>4)*8+j]; B-frag: B[k=(lane>>4)*8+j][n=lane&15];
// D: reg r = D[row=(lane>>4)*4+r][col=lane&15]   (verified R2)
// ---------------------------------------------------------------------------
__global__ __launch_bounds__(256, 2) void edge_kernel(
    const unsigned short* __restrict__ hbf,   // [NDET][32] bf16
    const int* __restrict__ nIdx,             // [NEDGE]
    const float* __restrict__ pairF,          // [NEDGE][32] fp32
    const float* __restrict__ W1,             // [96][64]
    const float* __restrict__ b1,
    const float* __restrict__ W2,             // [64][64]
    const float* __restrict__ b2,
    unsigned short* __restrict__ m_bf)        // [NDET][64] bf16
{
    __shared__ __align__(16) unsigned short lds[4][64 * 72];  // 36864 B: per-wave Y1 tiles; [0..] doubles as weight staging

    const int tid  = threadIdx.x;
    const int lane = tid & 63;
    const int wv   = tid >> 6;
    const int m16  = lane & 15;
    const int q    = lane >> 4;

    // ---- stage transposed bf16 weights: W1T[n*96+k] (6144), W2T at +6144 (n*64+k) ----
    unsigned short* st = &lds[0][0];
    for (int i = tid; i < 64 * 96; i += 256) {
        int n = i / 96, k = i - n * 96;
        st[i] = f2bf(W1[k * 64 + n]);
    }
    for (int i = tid; i < 64 * 64; i += 256) {
        int n = i >> 6, k = i & 63;
        st[6144 + i] = f2bf(W2[k * 64 + n]);
    }
    __syncthreads();

    // W1 B-frags in registers: ks0=pair rows 0..31, ks1=nbr rows 64..95, ks2=center rows 32..63
    short8 w1f[3][4];
#pragma unroll
    for (int nt = 0; nt < 4; nt++) {
        const unsigned short* base = &st[(nt * 16 + m16) * 96];
        w1f[0][nt] = *(const short8*)&base[q * 8];
        w1f[1][nt] = *(const short8*)&base[64 + q * 8];
        w1f[2][nt] = *(const short8*)&base[32 + q * 8];
    }
    float b1r[4], b2r[4];
#pragma unroll
    for (int nt = 0; nt < 4; nt++) {
        b1r[nt] = b1[nt * 16 + m16];
        b2r[nt] = b2[nt * 16 + m16];
    }
    __syncthreads();   // staging area free; becomes per-wave Y1 tiles

    unsigned short* Y1w = &lds[wv][0];
    const unsigned short* W2T = nullptr;  // W2 frags read from... (overwritten!) -> keep in regs instead
    (void)W2T;
    // W2 B-frags must be register-resident (staging LDS is reused as Y1 tiles)
    // (loaded above before the second syncthreads would be overwritten only by wave tiles 0..3;
    //  st[6144..] lives in lds[1]/[2] which ARE wave tiles -> so load them now, before reuse)
    // NOTE: loaded here, before any Y1 writes happen (post-sync, pre-loop) — safe.
    short8 w2f[2][4];
#pragma unroll
    for (int nt = 0; nt < 4; nt++) {
        w2f[0][nt] = *(const short8*)&st[6144 + (nt * 16 + m16) * 64 + q * 8];
        w2f[1][nt] = *(const short8*)&st[6144 + (nt * 16 + m16) * 64 + 32 + q * 8];
    }
    __syncthreads();

    const int wstride = (int)gridDim.x * 4;
    int g = blockIdx.x * 4 + wv;
    if (g >= NGROUP) return;

    // prefetch registers
    int    ni[4];
    float4 pv[4][2];
    short8 nb[4];
    short8 cf2[2];

#define PREF(gg)                                                                  \
    {                                                                             \
        const int E0p = (gg) * 64, d0p = (gg) * 2;                                \
        _Pragma("unroll")                                                         \
        for (int mt = 0; mt < 4; mt++) {                                          \
            int e = E0p + mt * 16 + m16;                                          \
            ni[mt] = nIdx[e];                                                     \
            const float* pr = pairF + (size_t)e * 32 + q * 8;                     \
            pv[mt][0] = *(const float4*)pr;                                       \
            pv[mt][1] = *(const float4*)(pr + 4);                                 \
            nb[mt] = *(const short8*)&hbf[(size_t)ni[mt] * 32 + q * 8];           \
        }                                                                         \
        cf2[0] = *(const short8*)&hbf[(size_t)d0p * 32 + q * 8];                  \
        cf2[1] = *(const short8*)&hbf[(size_t)(d0p + 1) * 32 + q * 8];            \
    }

    PREF(g);
    const short8 zr = {0, 0, 0, 0, 0, 0, 0, 0};

    while (true) {
        const int d0 = g * 2;
        // ---- consume prefetched data into A-frags ----
        short8 ap[4], an[4], ac[4];
#pragma unroll
        for (int mt = 0; mt < 4; mt++) {
            ap[mt] = pack8(pv[mt][0], pv[mt][1]);
            an[mt] = (ni[mt] == d0 + (mt >> 1)) ? zr : nb[mt];
            ac[mt] = cf2[mt >> 1];
        }
        const int gn = g + wstride;
        const bool more = (gn < NGROUP);
        PREF(more ? gn : g);   // dead loads on last iter

        // ---- MLP1: K=96, 48 MFMA ----
        f32x4 acc[4][4];
#pragma unroll
        for (int mt = 0; mt < 4; mt++)
#pragma unroll
            for (int nt = 0; nt < 4; nt++) {
                float c0 = b1r[nt];
                acc[mt][nt] = (f32x4){c0, c0, c0, c0};
            }
#pragma unroll
        for (int mt = 0; mt < 4; mt++)
#pragma unroll
            for (int nt = 0; nt < 4; nt++) {
                acc[mt][nt] = __builtin_amdgcn_mfma_f32_16x16x32_bf16(ap[mt], w1f[0][nt], acc[mt][nt], 0, 0, 0);
                acc[mt][nt] = __builtin_amdgcn_mfma_f32_16x16x32_bf16(an[mt], w1f[1][nt], acc[mt][nt], 0, 0, 0);
                acc[mt][nt] = __builtin_amdgcn_mfma_f32_16x16x32_bf16(ac[mt], w1f[2][nt], acc[mt][nt], 0, 0, 0);
            }

        // ---- Y1 = relu -> bf16 -> LDS (layout transform) ----
#pragma unroll
        for (int mt = 0; mt < 4; mt++)
#pragma unroll
            for (int nt = 0; nt < 4; nt++)
#pragma unroll
                for (int r = 0; r < 4; r++)
                    Y1w[(mt * 16 + q * 4 + r) * 72 + nt * 16 + m16] =
                        f2bf(fmaxf(acc[mt][nt][r], 0.0f));

        // ---- MLP2: K=64, 32 MFMA ----
        f32x4 acc2[4][4];
#pragma unroll
        for (int mt = 0; mt < 4; mt++)
#pragma unroll
            for (int nt = 0; nt < 4; nt++) {
                float c0 = b2r[nt];
                acc2[mt][nt] = (f32x4){c0, c0, c0, c0};
            }
#pragma unroll
        for (int ks = 0; ks < 2; ks++) {
            short8 af[4];
#pragma unroll
            for (int mt = 0; mt < 4; mt++)
                af[mt] = *(const short8*)&Y1w[(mt * 16 + m16) * 72 + ks * 32 + q * 8];
#pragma unroll
            for (int mt = 0; mt < 4; mt++)
#pragma unroll
                for (int nt = 0; nt < 4; nt++)
                    acc2[mt][nt] = __builtin_amdgcn_mfma_f32_16x16x32_bf16(af[mt], w2f[ks][nt], acc2[mt][nt], 0, 0, 0);
        }

        // ---- relu + per-det max (32 edges) + bf16 store ----
#pragma unroll
        for (int d = 0; d < 2; d++)
#pragma unroll
            for (int nt = 0; nt < 4; nt++) {
                float v = 0.0f;
#pragma unroll
                for (int mt = 2 * d; mt < 2 * d + 2; mt++)
#pragma unroll
                    for (int r = 0; r < 4; r++) v = fmaxf(v, acc2[mt][nt][r]);
                v = fmaxf(v, __shfl_xor(v, 16));
                v = fmaxf(v, __shfl_xor(v, 32));
                if (q == 0) m_bf[(size_t)(d0 + d) * 64 + nt * 16 + m16] = f2bf(v);
            }

        if (!more) break;
        g = gn;
    }
#undef PREF
}

// ---------------------------------------------------------------------------
// Kernel C: tail via MFMA. Wave = 64 dets.
// m[64,64]@Wm1 -> relu -> @Wm2 -> relu -> @Wo[64,128] -> +detF -> relu.
// ---------------------------------------------------------------------------
__global__ __launch_bounds__(256, 2) void tail_kernel(
    const float* __restrict__ detF,
    const unsigned short* __restrict__ m_bf,   // [NDET][64] bf16
    const float* __restrict__ Wm1, const float* __restrict__ bm1,
    const float* __restrict__ Wm2, const float* __restrict__ bm2,
    const float* __restrict__ Wo,  const float* __restrict__ bo,
    float* __restrict__ out)
{
    __shared__ __align__(16) unsigned short W1T[64 * 72];   // [n][k] bf16
    __shared__ __align__(16) unsigned short W2T[64 * 72];
    __shared__ __align__(16) unsigned short WoT[128 * 72];
    __shared__ __align__(16) unsigned short Tt[4][64 * 72]; // per-wave t tiles

    const int tid  = threadIdx.x;
    const int lane = tid & 63;
    const int wv   = tid >> 6;
    const int m16  = lane & 15;
    const int q    = lane >> 4;

    for (int i = tid; i < 64 * 64; i += 256) {
        int n = i >> 6, k = i & 63;
        W1T[n * 72 + k] = f2bf(Wm1[k * 64 + n]);
        W2T[n * 72 + k] = f2bf(Wm2[k * 64 + n]);
    }
    for (int i = tid; i < 128 * 64; i += 256) {
        int n = i >> 6, k = i & 63;
        WoT[n * 72 + k] = f2bf(Wo[k * 128 + n]);
    }
    __syncthreads();

    float bm1r[4], bm2r[4], bor[8];
#pragma unroll
    for (int nt = 0; nt < 4; nt++) {
        bm1r[nt] = bm1[nt * 16 + m16];
        bm2r[nt] = bm2[nt * 16 + m16];
    }
#pragma unroll
    for (int nt = 0; nt < 8; nt++) bor[nt] = bo[nt * 16 + m16];

    unsigned short* Tw = &Tt[wv][0];
    const int NTG = (NDET + 63) / 64;   // 782

    for (int gI = blockIdx.x * 4 + wv; gI < NTG; gI += (int)gridDim.x * 4) {
        const int d0 = gI * 64;

        // ---- GEMM1: A = m_bf rows (clamped), B = Wm1 ----
        f32x4 acc[4][4];
#pragma unroll
        for (int mt = 0; mt < 4; mt++)
#pragma unroll
            for (int nt = 0; nt < 4; nt++) {
                float c0 = bm1r[nt];
                acc[mt][nt] = (f32x4){c0, c0, c0, c0};
            }
#pragma unroll
        for (int ks = 0; ks < 2; ks++) {
            short8 af[4];
#pragma unroll
            for (int mt = 0; mt < 4; mt++) {
                int row = d0 + mt * 16 + m16;
                if (row >= NDET) row = NDET - 1;
                af[mt] = *(const short8*)&m_bf[(size_t)row * 64 + ks * 32 + q * 8];
            }
#pragma unroll
            for (int mt = 0; mt < 4; mt++)
#pragma unroll
                for (int nt = 0; nt < 4; nt++) {
                    short8 bf = *(const short8*)&W1T[(nt * 16 + m16) * 72 + ks * 32 + q * 8];
                    acc[mt][nt] = __builtin_amdgcn_mfma_f32_16x16x32_bf16(af[mt], bf, acc[mt][nt], 0, 0, 0);
                }
        }
        // t1 -> LDS
#pragma unroll
        for (int mt = 0; mt < 4; mt++)
#pragma unroll
            for (int nt = 0; nt < 4; nt++)
#pragma unroll
                for (int r = 0; r < 4; r++)
                    Tw[(mt * 16 + q * 4 + r) * 72 + nt * 16 + m16] =
                        f2bf(fmaxf(acc[mt][nt][r], 0.0f));

        // ---- GEMM2 ----
#pragma unroll
        for (int mt = 0; mt < 4; mt++)
#pragma unroll
            for (int nt = 0; nt < 4; nt++) {
                float c0 = bm2r[nt];
                acc[mt][nt] = (f32x4){c0, c0, c0, c0};
            }
#pragma unroll
        for (int ks = 0; ks < 2; ks++) {
            short8 af[4];
#pragma unroll
            for (int mt = 0; mt < 4; mt++)
                af[mt] = *(const short8*)&Tw[(mt * 16 + m16) * 72 + ks * 32 + q * 8];
#pragma unroll
            for (int mt = 0; mt < 4; mt++)
#pragma unroll
                for (int nt = 0; nt < 4; nt++) {
                    short8 bf = *(const short8*)&W2T[(nt * 16 + m16) * 72 + ks * 32 + q * 8];
                    acc[mt][nt] = __builtin_amdgcn_mfma_f32_16x16x32_bf16(af[mt], bf, acc[mt][nt], 0, 0, 0);
                }
        }
        // t2 -> LDS
#pragma unroll
        for (int mt = 0; mt < 4; mt++)
#pragma unroll
            for (int nt = 0; nt < 4; nt++)
#pragma unroll
                for (int r = 0; r < 4; r++)
                    Tw[(mt * 16 + q * 4 + r) * 72 + nt * 16 + m16] =
                        f2bf(fmaxf(acc[mt][nt][r], 0.0f));

        // A3 frags
        short8 a3[4][2];
#pragma unroll
        for (int ks = 0; ks < 2; ks++)
#pragma unroll
            for (int mt = 0; mt < 4; mt++)
                a3[mt][ks] = *(const short8*)&Tw[(mt * 16 + m16) * 72 + ks * 32 + q * 8];

        // ---- GEMM3 in two 64-col halves + epilogue ----
#pragma unroll
        for (int h2 = 0; h2 < 2; h2++) {
            f32x4 acc3[4][4];
#pragma unroll
            for (int mt = 0; mt < 4; mt++)
#pragma unroll
                for (int nt = 0; nt < 4; nt++) {
                    float c0 = bor[h2 * 4 + nt];
                    acc3[mt][nt] = (f32x4){c0, c0, c0, c0};
                }
#pragma unroll
            for (int ks = 0; ks < 2; ks++)
#pragma unroll
                for (int mt = 0; mt < 4; mt++)
#pragma unroll
                    for (int nt = 0; nt < 4; nt++) {
                        short8 bf = *(const short8*)&WoT[((h2 * 4 + nt) * 16 + m16) * 72 + ks * 32 + q * 8];
                        acc3[mt][nt] = __builtin_amdgcn_mfma_f32_16x16x32_bf16(a3[mt][ks], bf, acc3[mt][nt], 0, 0, 0);
                    }
#pragma unroll
            for (int mt = 0; mt < 4; mt++)
#pragma unroll
                for (int r = 0; r < 4; r++) {
                    int row = d0 + mt * 16 + q * 4 + r;
                    if (row < NDET) {
#pragma unroll
                        for (int nt = 0; nt < 4; nt++) {
                            int col = (h2 * 4 + nt) * 16 + m16;
                            float v = detF[(size_t)row * 128 + col] + acc3[mt][nt][r];
                            out[(size_t)row * 128 + col] = fmaxf(v, 0.0f);
                        }
                    }
                }
        }
    }
}

// ---------------------------------------------------------------------------
extern "C" void kernel_launch(void* const* d_in, const int* in_sizes, int n_in,
                              void* d_out, int out_size, void* d_ws, size_t ws_size,
                              hipStream_t stream)
{
    const float* detF  = (const float*)d_in[0];
    const int*   nIdx  = (const int*)d_in[2];
    const float* pairF = (const float*)d_in[3];
    const float* W_fc1 = (const float*)d_in[4];
    const float* b_fc1 = (const float*)d_in[5];
    const float* W_pw1 = (const float*)d_in[6];
    const float* b_pw1 = (const float*)d_in[7];
    const float* W_pw2 = (const float*)d_in[8];
    const float* b_pw2 = (const float*)d_in[9];
    const float* W_pm1 = (const float*)d_in[10];
    const float* b_pm1 = (const float*)d_in[11];
    const float* W_pm2 = (const float*)d_in[12];
    const float* b_pm2 = (const float*)d_in[13];
    const float* W_out = (const float*)d_in[14];
    const float* b_out = (const float*)d_in[15];
    float* out = (float*)d_out;

    unsigned short* hbf  = (unsigned short*)d_ws;          // [NDET][32] bf16
    unsigned short* m_bf = hbf + (size_t)NDET * 32;        // [NDET][64] bf16

    fc1_kernel<<<1024, 256, 0, stream>>>(detF, W_fc1, b_fc1, hbf);
    edge_kernel<<<1024, 256, 0, stream>>>(hbf, nIdx, pairF,
                                          W_pw1, b_pw1, W_pw2, b_pw2, m_bf);
    tail_kernel<<<256, 256, 0, stream>>>(detF, m_bf, W_pm1, b_pm1, W_pm2, b_pm2,
                                         W_out, b_out, out);
}

// Round 4
// 458.671 us; speedup vs baseline: 1.7177x; 1.0113x over previous
//
#include <hip/hip_runtime.h>

#define NDET 50000
#define DEG 32
#define NEDGE (NDET * DEG)
#define NGROUP (NEDGE / 64)   // 25000 groups of 2 dets / 64 edges

typedef __attribute__((ext_vector_type(8))) short short8;
typedef __attribute__((ext_vector_type(4))) float f32x4;

// round-half-up bf16 convert: 2 VALU ops, max extra error = half-ulp on ties
__device__ inline unsigned short f2bf(float x) {
    return (unsigned short)((__builtin_bit_cast(unsigned int, x) + 0x8000u) >> 16);
}

__device__ inline short8 pack8(float4 a, float4 b) {
    short8 r;
    r[0] = (short)f2bf(a.x); r[1] = (short)f2bf(a.y);
    r[2] = (short)f2bf(a.z); r[3] = (short)f2bf(a.w);
    r[4] = (short)f2bf(b.x); r[5] = (short)f2bf(b.y);
    r[6] = (short)f2bf(b.z); r[7] = (short)f2bf(b.w);
    return r;
}

// ---------------------------------------------------------------------------
// Kernel A: hbf = bf16(relu(detF @ W_fc1 + b_fc1))  via MFMA, K=128.
// Wave = 64 rows; 782 groups; each wave does exactly one group.
// A-frag: lane holds A[m=lane&15][k=(lane>>4)*8+j]; B-frag: B[k][n=lane&15];
// D: reg r = D[row=(lane>>4)*4+r][col=lane&15]
// ---------------------------------------------------------------------------
__global__ __launch_bounds__(256, 4) void fc1_kernel(
    const float* __restrict__ detF,     // [NDET][128]
    const float* __restrict__ W,        // [128][32]
    const float* __restrict__ b,        // [32]
    unsigned short* __restrict__ hbf)   // [NDET][32] bf16
{
    __shared__ __align__(16) unsigned short WT[32 * 136];  // [n][k], row stride 136

    const int tid  = threadIdx.x;
    const int lane = tid & 63;
    const int wv   = tid >> 6;
    const int m16  = lane & 15;
    const int q    = lane >> 4;

    for (int i = tid; i < 32 * 128; i += 256) {
        int n = i >> 7, k = i & 127;
        WT[n * 136 + k] = f2bf(W[k * 32 + n]);
    }
    __syncthreads();

    const int g = blockIdx.x * 4 + wv;
    if (g >= (NDET + 63) / 64) return;
    const int d0 = g * 64;

    f32x4 acc[4][2];
#pragma unroll
    for (int nt = 0; nt < 2; nt++) {
        float c0 = b[nt * 16 + m16];
#pragma unroll
        for (int mt = 0; mt < 4; mt++) acc[mt][nt] = (f32x4){c0, c0, c0, c0};
    }

#pragma unroll
    for (int ks = 0; ks < 4; ks++) {
#pragma unroll
        for (int mt = 0; mt < 4; mt++) {
            int row = d0 + mt * 16 + m16;
            if (row >= NDET) row = NDET - 1;
            const float* pr = detF + (size_t)row * 128 + ks * 32 + q * 8;
            short8 a = pack8(*(const float4*)pr, *(const float4*)(pr + 4));
#pragma unroll
            for (int nt = 0; nt < 2; nt++) {
                short8 bf = *(const short8*)&WT[(nt * 16 + m16) * 136 + ks * 32 + q * 8];
                acc[mt][nt] = __builtin_amdgcn_mfma_f32_16x16x32_bf16(a, bf, acc[mt][nt], 0, 0, 0);
            }
        }
    }

#pragma unroll
    for (int mt = 0; mt < 4; mt++)
#pragma unroll
        for (int r = 0; r < 4; r++) {
            int row = d0 + mt * 16 + q * 4 + r;
            if (row < NDET) {
#pragma unroll
                for (int nt = 0; nt < 2; nt++)
                    hbf[(size_t)row * 32 + nt * 16 + m16] = f2bf(fmaxf(acc[mt][nt][r], 0.0f));
            }
        }
}

// ---------------------------------------------------------------------------
// Kernel B: edge MLP. W2 frags moved to dedicated LDS (frees 32 VGPRs ->
// 3 waves/SIMD at __launch_bounds__(256,3)). Otherwise the R4 structure:
// wave-private, direct-to-register A-frags, 1-deep prefetch, MLP1 K=96.
// ---------------------------------------------------------------------------
__global__ __launch_bounds__(256, 3) void edge_kernel(
    const unsigned short* __restrict__ hbf,   // [NDET][32] bf16
    const int* __restrict__ nIdx,             // [NEDGE]
    const float* __restrict__ pairF,          // [NEDGE][32] fp32
    const float* __restrict__ W1,             // [96][64]
    const float* __restrict__ b1,
    const float* __restrict__ W2,             // [64][64]
    const float* __restrict__ b2,
    unsigned short* __restrict__ m_bf)        // [NDET][64] bf16
{
    __shared__ __align__(16) unsigned short Y1s[4][64 * 72];  // 36864 B (also W1 staging)
    __shared__ __align__(16) unsigned short W2T[64 * 72];     // 9216 B, persistent
    // 46080 B total -> 3 blocks/CU

    const int tid  = threadIdx.x;
    const int lane = tid & 63;
    const int wv   = tid >> 6;
    const int m16  = lane & 15;
    const int q    = lane >> 4;

    // stage W1T [n][96] into Y1s-flat; W2T [n][k] pad 72 persistent
    unsigned short* st = &Y1s[0][0];
    for (int i = tid; i < 64 * 96; i += 256) {
        int n = i / 96, k = i - n * 96;
        st[i] = f2bf(W1[k * 64 + n]);
    }
    for (int i = tid; i < 64 * 64; i += 256) {
        int n = i >> 6, k = i & 63;
        W2T[n * 72 + k] = f2bf(W2[k * 64 + n]);
    }
    __syncthreads();

    // W1 B-frags in registers: ks0=pair(rows 0..31), ks1=nbr(64..95), ks2=center(32..63)
    short8 w1f[3][4];
#pragma unroll
    for (int nt = 0; nt < 4; nt++) {
        const unsigned short* base = &st[(nt * 16 + m16) * 96];
        w1f[0][nt] = *(const short8*)&base[q * 8];
        w1f[1][nt] = *(const short8*)&base[64 + q * 8];
        w1f[2][nt] = *(const short8*)&base[32 + q * 8];
    }
    float b1r[4], b2r[4];
#pragma unroll
    for (int nt = 0; nt < 4; nt++) {
        b1r[nt] = b1[nt * 16 + m16];
        b2r[nt] = b2[nt * 16 + m16];
    }
    __syncthreads();   // W1 staging area free -> per-wave Y1 tiles

    unsigned short* Y1w = &Y1s[wv][0];

    const int wstride = (int)gridDim.x * 4;
    int g = blockIdx.x * 4 + wv;
    if (g >= NGROUP) return;

    int    ni[4];
    float4 pv[4][2];
    short8 nb[4];
    short8 cf2[2];

#define PREF(gg)                                                                  \
    {                                                                             \
        const int E0p = (gg) * 64, d0p = (gg) * 2;                                \
        _Pragma("unroll")                                                         \
        for (int mt = 0; mt < 4; mt++) {                                          \
            int e = E0p + mt * 16 + m16;                                          \
            ni[mt] = nIdx[e];                                                     \
            const float* pr = pairF + (size_t)e * 32 + q * 8;                     \
            pv[mt][0] = *(const float4*)pr;                                       \
            pv[mt][1] = *(const float4*)(pr + 4);                                 \
            nb[mt] = *(const short8*)&hbf[(size_t)ni[mt] * 32 + q * 8];           \
        }                                                                         \
        cf2[0] = *(const short8*)&hbf[(size_t)d0p * 32 + q * 8];                  \
        cf2[1] = *(const short8*)&hbf[(size_t)(d0p + 1) * 32 + q * 8];            \
    }

    PREF(g);
    const short8 zr = {0, 0, 0, 0, 0, 0, 0, 0};

    while (true) {
        const int d0 = g * 2;
        short8 ap[4], an[4], ac[4];
#pragma unroll
        for (int mt = 0; mt < 4; mt++) {
            ap[mt] = pack8(pv[mt][0], pv[mt][1]);
            an[mt] = (ni[mt] == d0 + (mt >> 1)) ? zr : nb[mt];
            ac[mt] = cf2[mt >> 1];
        }
        const int gn = g + wstride;
        const bool more = (gn < NGROUP);
        PREF(more ? gn : g);   // dead loads on last iter

        // ---- MLP1: K=96, 48 MFMA ----
        f32x4 acc[4][4];
#pragma unroll
        for (int mt = 0; mt < 4; mt++)
#pragma unroll
            for (int nt = 0; nt < 4; nt++) {
                float c0 = b1r[nt];
                acc[mt][nt] = (f32x4){c0, c0, c0, c0};
            }
#pragma unroll
        for (int mt = 0; mt < 4; mt++)
#pragma unroll
            for (int nt = 0; nt < 4; nt++) {
                acc[mt][nt] = __builtin_amdgcn_mfma_f32_16x16x32_bf16(ap[mt], w1f[0][nt], acc[mt][nt], 0, 0, 0);
                acc[mt][nt] = __builtin_amdgcn_mfma_f32_16x16x32_bf16(an[mt], w1f[1][nt], acc[mt][nt], 0, 0, 0);
                acc[mt][nt] = __builtin_amdgcn_mfma_f32_16x16x32_bf16(ac[mt], w1f[2][nt], acc[mt][nt], 0, 0, 0);
            }

        // ---- Y1 = relu -> bf16 -> LDS (layout transform) ----
#pragma unroll
        for (int mt = 0; mt < 4; mt++)
#pragma unroll
            for (int nt = 0; nt < 4; nt++)
#pragma unroll
                for (int r = 0; r < 4; r++)
                    Y1w[(mt * 16 + q * 4 + r) * 72 + nt * 16 + m16] =
                        f2bf(fmaxf(acc[mt][nt][r], 0.0f));

        // ---- MLP2: K=64, 32 MFMA (W2 frags from persistent LDS) ----
        f32x4 acc2[4][4];
#pragma unroll
        for (int mt = 0; mt < 4; mt++)
#pragma unroll
            for (int nt = 0; nt < 4; nt++) {
                float c0 = b2r[nt];
                acc2[mt][nt] = (f32x4){c0, c0, c0, c0};
            }
#pragma unroll
        for (int ks = 0; ks < 2; ks++) {
            short8 af[4];
#pragma unroll
            for (int mt = 0; mt < 4; mt++)
                af[mt] = *(const short8*)&Y1w[(mt * 16 + m16) * 72 + ks * 32 + q * 8];
#pragma unroll
            for (int nt = 0; nt < 4; nt++) {
                short8 wf = *(const short8*)&W2T[(nt * 16 + m16) * 72 + ks * 32 + q * 8];
#pragma unroll
                for (int mt = 0; mt < 4; mt++)
                    acc2[mt][nt] = __builtin_amdgcn_mfma_f32_16x16x32_bf16(af[mt], wf, acc2[mt][nt], 0, 0, 0);
            }
        }

        // ---- relu + per-det max (32 edges) + bf16 store ----
#pragma unroll
        for (int d = 0; d < 2; d++)
#pragma unroll
            for (int nt = 0; nt < 4; nt++) {
                float v = 0.0f;
#pragma unroll
                for (int mt = 2 * d; mt < 2 * d + 2; mt++)
#pragma unroll
                    for (int r = 0; r < 4; r++) v = fmaxf(v, acc2[mt][nt][r]);
                v = fmaxf(v, __shfl_xor(v, 16));
                v = fmaxf(v, __shfl_xor(v, 32));
                if (q == 0) m_bf[(size_t)(d0 + d) * 64 + nt * 16 + m16] = f2bf(v);
            }

        if (!more) break;
        g = gn;
    }
#undef PREF
}

// ---------------------------------------------------------------------------
// Kernel C: tail via MFMA (unchanged structure from R4).
// ---------------------------------------------------------------------------
__global__ __launch_bounds__(256, 2) void tail_kernel(
    const float* __restrict__ detF,
    const unsigned short* __restrict__ m_bf,   // [NDET][64] bf16
    const float* __restrict__ Wm1, const float* __restrict__ bm1,
    const float* __restrict__ Wm2, const float* __restrict__ bm2,
    const float* __restrict__ Wo,  const float* __restrict__ bo,
    float* __restrict__ out)
{
    __shared__ __align__(16) unsigned short W1T[64 * 72];
    __shared__ __align__(16) unsigned short W2T[64 * 72];
    __shared__ __align__(16) unsigned short WoT[128 * 72];
    __shared__ __align__(16) unsigned short Tt[4][64 * 72];

    const int tid  = threadIdx.x;
    const int lane = tid & 63;
    const int wv   = tid >> 6;
    const int m16  = lane & 15;
    const int q    = lane >> 4;

    for (int i = tid; i < 64 * 64; i += 256) {
        int n = i >> 6, k = i & 63;
        W1T[n * 72 + k] = f2bf(Wm1[k * 64 + n]);
        W2T[n * 72 + k] = f2bf(Wm2[k * 64 + n]);
    }
    for (int i = tid; i < 128 * 64; i += 256) {
        int n = i >> 6, k = i & 63;
        WoT[n * 72 + k] = f2bf(Wo[k * 128 + n]);
    }
    __syncthreads();

    float bm1r[4], bm2r[4], bor[8];
#pragma unroll
    for (int nt = 0; nt < 4; nt++) {
        bm1r[nt] = bm1[nt * 16 + m16];
        bm2r[nt] = bm2[nt * 16 + m16];
    }
#pragma unroll
    for (int nt = 0; nt < 8; nt++) bor[nt] = bo[nt * 16 + m16];

    unsigned short* Tw = &Tt[wv][0];
    const int NTG = (NDET + 63) / 64;   // 782

    for (int gI = blockIdx.x * 4 + wv; gI < NTG; gI += (int)gridDim.x * 4) {
        const int d0 = gI * 64;

        f32x4 acc[4][4];
#pragma unroll
        for (int mt = 0; mt < 4; mt++)
#pragma unroll
            for (int nt = 0; nt < 4; nt++) {
                float c0 = bm1r[nt];
                acc[mt][nt] = (f32x4){c0, c0, c0, c0};
            }
#pragma unroll
        for (int ks = 0; ks < 2; ks++) {
            short8 af[4];
#pragma unroll
            for (int mt = 0; mt < 4; mt++) {
                int row = d0 + mt * 16 + m16;
                if (row >= NDET) row = NDET - 1;
                af[mt] = *(const short8*)&m_bf[(size_t)row * 64 + ks * 32 + q * 8];
            }
#pragma unroll
            for (int mt = 0; mt < 4; mt++)
#pragma unroll
                for (int nt = 0; nt < 4; nt++) {
                    short8 bf = *(const short8*)&W1T[(nt * 16 + m16) * 72 + ks * 32 + q * 8];
                    acc[mt][nt] = __builtin_amdgcn_mfma_f32_16x16x32_bf16(af[mt], bf, acc[mt][nt], 0, 0, 0);
                }
        }
#pragma unroll
        for (int mt = 0; mt < 4; mt++)
#pragma unroll
            for (int nt = 0; nt < 4; nt++)
#pragma unroll
                for (int r = 0; r < 4; r++)
                    Tw[(mt * 16 + q * 4 + r) * 72 + nt * 16 + m16] =
                        f2bf(fmaxf(acc[mt][nt][r], 0.0f));

#pragma unroll
        for (int mt = 0; mt < 4; mt++)
#pragma unroll
            for (int nt = 0; nt < 4; nt++) {
                float c0 = bm2r[nt];
                acc[mt][nt] = (f32x4){c0, c0, c0, c0};
            }
#pragma unroll
        for (int ks = 0; ks < 2; ks++) {
            short8 af[4];
#pragma unroll
            for (int mt = 0; mt < 4; mt++)
                af[mt] = *(const short8*)&Tw[(mt * 16 + m16) * 72 + ks * 32 + q * 8];
#pragma unroll
            for (int mt = 0; mt < 4; mt++)
#pragma unroll
                for (int nt = 0; nt < 4; nt++) {
                    short8 bf = *(const short8*)&W2T[(nt * 16 + m16) * 72 + ks * 32 + q * 8];
                    acc[mt][nt] = __builtin_amdgcn_mfma_f32_16x16x32_bf16(af[mt], bf, acc[mt][nt], 0, 0, 0);
                }
        }
#pragma unroll
        for (int mt = 0; mt < 4; mt++)
#pragma unroll
            for (int nt = 0; nt < 4; nt++)
#pragma unroll
                for (int r = 0; r < 4; r++)
                    Tw[(mt * 16 + q * 4 + r) * 72 + nt * 16 + m16] =
                        f2bf(fmaxf(acc[mt][nt][r], 0.0f));

        short8 a3[4][2];
#pragma unroll
        for (int ks = 0; ks < 2; ks++)
#pragma unroll
            for (int mt = 0; mt < 4; mt++)
                a3[mt][ks] = *(const short8*)&Tw[(mt * 16 + m16) * 72 + ks * 32 + q * 8];

#pragma unroll
        for (int h2 = 0; h2 < 2; h2++) {
            f32x4 acc3[4][4];
#pragma unroll
            for (int mt = 0; mt < 4; mt++)
#pragma unroll
                for (int nt = 0; nt < 4; nt++) {
                    float c0 = bor[h2 * 4 + nt];
                    acc3[mt][nt] = (f32x4){c0, c0, c0, c0};
                }
#pragma unroll
            for (int ks = 0; ks < 2; ks++)
#pragma unroll
                for (int mt = 0; mt < 4; mt++)
#pragma unroll
                    for (int nt = 0; nt < 4; nt++) {
                        short8 bf = *(const short8*)&WoT[((h2 * 4 + nt) * 16 + m16) * 72 + ks * 32 + q * 8];
                        acc3[mt][nt] = __builtin_amdgcn_mfma_f32_16x16x32_bf16(a3[mt][ks], bf, acc3[mt][nt], 0, 0, 0);
                    }
#pragma unroll
            for (int mt = 0; mt < 4; mt++)
#pragma unroll
                for (int r = 0; r < 4; r++) {
                    int row = d0 + mt * 16 + q * 4 + r;
                    if (row < NDET) {
#pragma unroll
                        for (int nt = 0; nt < 4; nt++) {
                            int col = (h2 * 4 + nt) * 16 + m16;
                            float v = detF[(size_t)row * 128 + col] + acc3[mt][nt][r];
                            out[(size_t)row * 128 + col] = fmaxf(v, 0.0f);
                        }
                    }
                }
        }
    }
}

// ---------------------------------------------------------------------------
extern "C" void kernel_launch(void* const* d_in, const int* in_sizes, int n_in,
                              void* d_out, int out_size, void* d_ws, size_t ws_size,
                              hipStream_t stream)
{
    const float* detF  = (const float*)d_in[0];
    const int*   nIdx  = (const int*)d_in[2];
    const float* pairF = (const float*)d_in[3];
    const float* W_fc1 = (const float*)d_in[4];
    const float* b_fc1 = (const float*)d_in[5];
    const float* W_pw1 = (const float*)d_in[6];
    const float* b_pw1 = (const float*)d_in[7];
    const float* W_pw2 = (const float*)d_in[8];
    const float* b_pw2 = (const float*)d_in[9];
    const float* W_pm1 = (const float*)d_in[10];
    const float* b_pm1 = (const float*)d_in[11];
    const float* W_pm2 = (const float*)d_in[12];
    const float* b_pm2 = (const float*)d_in[13];
    const float* W_out = (const float*)d_in[14];
    const float* b_out = (const float*)d_in[15];
    float* out = (float*)d_out;

    unsigned short* hbf  = (unsigned short*)d_ws;          // [NDET][32] bf16
    unsigned short* m_bf = hbf + (size_t)NDET * 32;        // [NDET][64] bf16

    fc1_kernel<<<(NDET + 255) / 256, 256, 0, stream>>>(detF, W_fc1, b_fc1, hbf);
    edge_kernel<<<768, 256, 0, stream>>>(hbf, nIdx, pairF,
                                         W_pw1, b_pw1, W_pw2, b_pw2, m_bf);
    tail_kernel<<<256, 256, 0, stream>>>(detF, m_bf, W_pm1, b_pm1, W_pm2, b_pm2,
                                         W_out, b_out, out);
}